// Round 4
// baseline (28.907 us; speedup 1.0000x reference)
//
#include <hip/hip_runtime.h>

// Problem constants (from reference): feat (32, 64, 112, 112) fp32
#define BB 32
#define CC 64
#define HH 112
#define WW 112
#define HW (HH * WW)          // 12544
#define Q4 (HW / 4)           // 3136 float4-quads per image
#define KS 14
#define HP (HH - KS + 1)      // 99
#define WP (WW - KS + 1)      // 99

#define BR 11                 // pooled rows per band
#define NB 9                  // 9 * 11 = 99 = HP exactly

#define QPB 64                // quads per block (chan kernel)
#define BPI (Q4 / QPB)        // 49 blocks per image (3136/64, exact)

// Kernel 1: s2[b,h,w] = (sum_c feat[b,c,h,w])^2.
// 4-way channel split: block = 4 channel-groups x 64 quads; each thread sums
// 16 channels, LDS-combine, group 0 squares+stores. 1568 blocks -> 3136 waves
// (24.5/CU) vs previous 6.1/CU.
__global__ __launch_bounds__(256) void chan_sum_sq4(const float* __restrict__ feat,
                                                    float* __restrict__ s2) {
    __shared__ float4 part[4][QPB];
    const int blk = blockIdx.x;          // 0 .. BB*BPI-1
    const int b = blk / BPI;
    const int q0 = (blk % BPI) * QPB;    // quad base within image
    const int tid = threadIdx.x;
    const int g = tid >> 6;              // channel group 0..3 (= wave id)
    const int q = tid & 63;

    const float4* base = reinterpret_cast<const float4*>(feat)
        + (size_t)b * CC * Q4 + (size_t)(g * 16) * Q4 + q0 + q;
    float4 acc = make_float4(0.f, 0.f, 0.f, 0.f);
#pragma unroll
    for (int c = 0; c < 16; ++c) {
        float4 v = base[(size_t)c * Q4];
        acc.x += v.x; acc.y += v.y; acc.z += v.z; acc.w += v.w;
    }
    part[g][q] = acc;
    __syncthreads();
    if (g == 0) {
        float4 p0 = part[0][q], p1 = part[1][q], p2 = part[2][q], p3 = part[3][q];
        float sx = p0.x + p1.x + p2.x + p3.x;
        float sy = p0.y + p1.y + p2.y + p3.y;
        float sz = p0.z + p1.z + p2.z + p3.z;
        float sw = p0.w + p1.w + p2.w + p3.w;
        float4 o;
        o.x = sx * sx; o.y = sy * sy; o.z = sz * sz; o.w = sw * sw;
        reinterpret_cast<float4*>(s2)[(size_t)b * Q4 + q0 + q] = o;
    }
}

// Kernel 2: band-tiled fused pooling + sim (unchanged from R3, 27.4us version).
__global__ __launch_bounds__(256) void pool_sim_band(const float* __restrict__ s2,
                                                     float* __restrict__ out) {
    __shared__ float hbuf[(BR + 2 + KS - 1) * WP];  // up to 26 rows of h-sums
    __shared__ float pbuf[(BR + 2) * WP];           // up to 13 rows of pooled

    const int b = blockIdx.y;
    const int band = blockIdx.x;
    const int r0 = band * BR;
    const int rend = min(r0 + BR, HP);
    const int pstart = max(r0 - 1, 0);
    const int pend = min(r0 + BR + 1, HP);
    const int pcount = pend - pstart;
    const int hcount = pcount + KS - 1;
    const int tid = threadIdx.x;
    const float* img = s2 + (size_t)b * HW;

    // Horizontal 14-tap sums for rows [pstart, pstart+hcount)
    for (int i = tid; i < hcount * WP; i += 256) {
        int hr = i / WP;
        int wp = i - hr * WP;
        const float* row = img + (pstart + hr) * WW + wp;
        float s = 0.f;
#pragma unroll
        for (int k = 0; k < KS; ++k) s += row[k];
        hbuf[i] = s;
    }
    __syncthreads();

    // Vertical 14-tap sums * 1/196 for pooled rows [pstart, pend)
    for (int i = tid; i < pcount * WP; i += 256) {
        int pr = i / WP;
        int wp = i - pr * WP;
        const float* col = hbuf + pr * WP + wp;
        float s = 0.f;
#pragma unroll
        for (int k = 0; k < KS; ++k) s += col[k * WP];
        pbuf[i] = s * (1.f / (float)(KS * KS));
    }
    __syncthreads();

    // Sim: out = C^2 * center * (zero-padded 8-neighbor sum), rows [r0, rend)
    float* ob = out + (size_t)b * HP * WP;
    for (int i = tid; i < (rend - r0) * WP; i += 256) {
        int rr = i / WP;
        int wp = i - rr * WP;
        int hp = r0 + rr;
        float center = pbuf[(hp - pstart) * WP + wp];
        float ns = 0.f;
#pragma unroll
        for (int dy = -1; dy <= 1; ++dy) {
#pragma unroll
            for (int dx = -1; dx <= 1; ++dx) {
                if (dy == 0 && dx == 0) continue;
                int y = hp + dy, x = wp + dx;
                if (y >= 0 && y < HP && x >= 0 && x < WP) {
                    ns += pbuf[(y - pstart) * WP + x];
                }
            }
        }
        ob[hp * WP + wp] = (float)(CC * CC) * center * ns;
    }
}

extern "C" void kernel_launch(void* const* d_in, const int* in_sizes, int n_in,
                              void* d_out, int out_size, void* d_ws, size_t ws_size,
                              hipStream_t stream) {
    const float* feat = (const float*)d_in[0];
    float* out = (float*)d_out;
    float* s2 = (float*)d_ws;  // BB*HW = 401,408 floats = 1.6 MB

    chan_sum_sq4<<<BB * BPI, 256, 0, stream>>>(feat, s2);
    {
        dim3 grid(NB, BB);
        pool_sim_band<<<grid, 256, 0, stream>>>(s2, out);
    }
}